// Round 2
// baseline (514.751 us; speedup 1.0000x reference)
//
#include <hip/hip_runtime.h>
#include <hip/hip_bf16.h>

// Sparse conv, two-phase:
//   sort chain: invert out_map (count -> scan -> scatter msg indices)
//   phase A:    gather x -> bf16 MFMA GEMM per offset -> stream bf16 messages to ws
//   phase B:    per output row, gather+sum its contribution rows, one write
// Replaces 113M fp32 atomics (302 G/s L2-RMW bound) with 3.5M int atomics.

typedef __attribute__((ext_vector_type(8))) short bf16x8;
typedef __attribute__((ext_vector_type(4))) float f32x4;

constexpr int KOFF = 27;
constexpr int M = 65536;
constexpr int CIN = 64;
constexpr int COUT = 64;
constexpr int NVOX = 262144;
constexpr int NMSG = KOFF * M;                 // 1,769,472
constexpr int TM_BLOCK = 512;
constexpr int TILES_PER_K = M / TM_BLOCK;      // 128
constexpr int SUBTILES = TM_BLOCK / (4 * 16);  // 8

// f32 -> bf16 round-to-nearest-even
static __device__ __forceinline__ short f2bf(float f) {
  unsigned u = __builtin_bit_cast(unsigned, f);
  unsigned r = (u + 0x7FFFu + ((u >> 16) & 1u)) >> 16;
  return (short)r;
}
static __device__ __forceinline__ float bf2f(unsigned short h) {
  return __builtin_bit_cast(float, (unsigned)h << 16);
}
static __device__ __forceinline__ bf16x8 pack8(float4 p, float4 q) {
  bf16x8 r;
  r[0] = f2bf(p.x); r[1] = f2bf(p.y); r[2] = f2bf(p.z); r[3] = f2bf(p.w);
  r[4] = f2bf(q.x); r[5] = f2bf(q.y); r[6] = f2bf(q.z); r[7] = f2bf(q.w);
  return r;
}

// ---------------- sort chain ----------------

__global__ __launch_bounds__(256) void count_kernel(const int* __restrict__ out_map,
                                                    int* __restrict__ count) {
  int i = blockIdx.x * 256 + threadIdx.x;  // grid sized exactly NMSG/256
  atomicAdd(&count[out_map[i]], 1);
}

__global__ __launch_bounds__(256) void scan1_kernel(const int* __restrict__ count,
                                                    int* __restrict__ offsets,
                                                    int* __restrict__ blockSums) {
  __shared__ int s[256];
  int t = threadIdx.x, i = blockIdx.x * 256 + t;
  int c = count[i];
  s[t] = c; __syncthreads();
  for (int off = 1; off < 256; off <<= 1) {
    int add = (t >= off) ? s[t - off] : 0;
    __syncthreads(); s[t] += add; __syncthreads();
  }
  offsets[i] = s[t] - c;                       // block-local exclusive
  if (t == 255) blockSums[blockIdx.x] = s[t];  // block total
}

__global__ __launch_bounds__(256) void scan2_kernel(int* __restrict__ blockSums) {
  // 1024 block sums, 256 threads, 4 each; in-place -> exclusive bases
  __shared__ int s[256];
  int t = threadIdx.x;
  int v[4]; int sum = 0;
#pragma unroll
  for (int j = 0; j < 4; ++j) { v[j] = blockSums[t * 4 + j]; sum += v[j]; }
  s[t] = sum; __syncthreads();
  for (int off = 1; off < 256; off <<= 1) {
    int add = (t >= off) ? s[t - off] : 0;
    __syncthreads(); s[t] += add; __syncthreads();
  }
  int run = s[t] - sum;
#pragma unroll
  for (int j = 0; j < 4; ++j) { int c = v[j]; blockSums[t * 4 + j] = run; run += c; }
}

__global__ __launch_bounds__(256) void scan3_kernel(int* __restrict__ offsets,
                                                    const int* __restrict__ blockBase,
                                                    int* __restrict__ cursor) {
  int i = blockIdx.x * 256 + threadIdx.x;
  int o = offsets[i] + blockBase[blockIdx.x];
  offsets[i] = o;
  cursor[i] = o;
}

__global__ __launch_bounds__(256) void scatter_kernel(const int* __restrict__ out_map,
                                                      int* __restrict__ cursor,
                                                      int* __restrict__ list) {
  int i = blockIdx.x * 256 + threadIdx.x;  // message index (k*M+m), grid = NMSG/256
  int o = out_map[i];
  int pos = atomicAdd(&cursor[o], 1);
  list[pos] = i;
}

// ---------------- phase A: GEMM -> bf16 message stream ----------------

__global__ __launch_bounds__(256) void gemm_msg_kernel(
    const float* __restrict__ x, const float* __restrict__ W,
    const int* __restrict__ in_map, unsigned short* __restrict__ msg) {
  const int k = blockIdx.x / TILES_PER_K;
  const int mblock = (blockIdx.x % TILES_PER_K) * TM_BLOCK;
  const int wave = threadIdx.x >> 6;
  const int l = threadIdx.x & 63;
  const int g = l >> 4;
  const int lr = l & 15;

  // B fragments: bfrag[t][u][j] = W[k][u*32 + g*8 + j][t*16 + lr]
  bf16x8 bfrag[4][2];
  const float* Wk = W + k * (CIN * COUT);
#pragma unroll
  for (int t = 0; t < 4; ++t)
#pragma unroll
    for (int u = 0; u < 2; ++u)
#pragma unroll
      for (int j = 0; j < 8; ++j)
        bfrag[t][u][j] = f2bf(Wk[(u * 32 + g * 8 + j) * COUT + t * 16 + lr]);

  const int mwave = mblock + wave * (TM_BLOCK / 4);
#pragma unroll 1
  for (int s = 0; s < SUBTILES; ++s) {
    const int mbase = mwave + s * 16;
    const int in_idx = in_map[k * M + mbase + lr];
    const float* xr = x + (size_t)in_idx * CIN + g * 8;
    float4 x0 = *(const float4*)(xr);
    float4 x1 = *(const float4*)(xr + 4);
    float4 x2 = *(const float4*)(xr + 32);
    float4 x3 = *(const float4*)(xr + 36);
    bf16x8 a0 = pack8(x0, x1);
    bf16x8 a1 = pack8(x2, x3);

    f32x4 acc[4] = {{0.f,0.f,0.f,0.f},{0.f,0.f,0.f,0.f},{0.f,0.f,0.f,0.f},{0.f,0.f,0.f,0.f}};
#pragma unroll
    for (int t = 0; t < 4; ++t) {
      acc[t] = __builtin_amdgcn_mfma_f32_16x16x32_bf16(a0, bfrag[t][0], acc[t], 0, 0, 0);
      acc[t] = __builtin_amdgcn_mfma_f32_16x16x32_bf16(a1, bfrag[t][1], acc[t], 0, 0, 0);
    }

    // Message row layout (position p = lr*4 + t holds channel t*16+lr):
    // lane (g,lr) stores 4 packed bf16 (8B) for row mbase+g*4+r.
    const size_t mrow = (size_t)k * M + mbase + g * 4;
#pragma unroll
    for (int r = 0; r < 4; ++r) {
      ushort4 h;
      h.x = (unsigned short)f2bf(acc[0][r]);
      h.y = (unsigned short)f2bf(acc[1][r]);
      h.z = (unsigned short)f2bf(acc[2][r]);
      h.w = (unsigned short)f2bf(acc[3][r]);
      *(ushort4*)(msg + (mrow + r) * 64 + lr * 4) = h;
    }
  }
}

// ---------------- phase B: per-row gather + sum ----------------

__global__ __launch_bounds__(256) void gather_out_kernel(
    const unsigned short* __restrict__ msg, const int* __restrict__ list,
    const int* __restrict__ offsets, const int* __restrict__ count,
    float* __restrict__ out) {
  const int o = (blockIdx.x * 256 + threadIdx.x) >> 6;  // one wave per output row
  const int p = threadIdx.x & 63;
  const int n = count[o];
  const int base = offsets[o];
  float acc = 0.f;
  int j = 0;
  for (; j + 1 < n; j += 2) {  // 2-way unroll for MLP
    int i0 = list[base + j];
    int i1 = list[base + j + 1];
    unsigned short a = msg[(size_t)i0 * 64 + p];
    unsigned short b = msg[(size_t)i1 * 64 + p];
    acc += bf2f(a);
    acc += bf2f(b);
  }
  if (j < n) acc += bf2f(msg[(size_t)list[base + j] * 64 + p]);
  const int chan = ((p & 3) << 4) | (p >> 2);  // invert msg position permutation
  out[(size_t)o * 64 + chan] = acc;            // every row written: no memset needed
}

// ---------------- fallback (round-1 atomic kernel) ----------------

__global__ __launch_bounds__(256) void spconv_atomic_kernel(
    const float* __restrict__ x, const float* __restrict__ W,
    const int* __restrict__ in_map, const int* __restrict__ out_map,
    float* __restrict__ out) {
  const int k = blockIdx.x / TILES_PER_K;
  const int mblock = (blockIdx.x % TILES_PER_K) * TM_BLOCK;
  const int wave = threadIdx.x >> 6;
  const int l = threadIdx.x & 63;
  const int g = l >> 4;
  const int lr = l & 15;
  bf16x8 bfrag[4][2];
  const float* Wk = W + k * (CIN * COUT);
#pragma unroll
  for (int t = 0; t < 4; ++t)
#pragma unroll
    for (int u = 0; u < 2; ++u)
#pragma unroll
      for (int j = 0; j < 8; ++j)
        bfrag[t][u][j] = f2bf(Wk[(u * 32 + g * 8 + j) * COUT + t * 16 + lr]);
  const int mwave = mblock + wave * (TM_BLOCK / 4);
#pragma unroll 1
  for (int s = 0; s < SUBTILES; ++s) {
    const int mbase = mwave + s * 16;
    const int in_idx = in_map[k * M + mbase + lr];
    const float* xr = x + (size_t)in_idx * CIN + g * 8;
    float4 x0 = *(const float4*)(xr);
    float4 x1 = *(const float4*)(xr + 4);
    float4 x2 = *(const float4*)(xr + 32);
    float4 x3 = *(const float4*)(xr + 36);
    bf16x8 a0 = pack8(x0, x1);
    bf16x8 a1 = pack8(x2, x3);
    f32x4 acc[4] = {{0.f,0.f,0.f,0.f},{0.f,0.f,0.f,0.f},{0.f,0.f,0.f,0.f},{0.f,0.f,0.f,0.f}};
#pragma unroll
    for (int t = 0; t < 4; ++t) {
      acc[t] = __builtin_amdgcn_mfma_f32_16x16x32_bf16(a0, bfrag[t][0], acc[t], 0, 0, 0);
      acc[t] = __builtin_amdgcn_mfma_f32_16x16x32_bf16(a1, bfrag[t][1], acc[t], 0, 0, 0);
    }
    const int obase = k * M + mbase + g * 4;
    int oidx[4];
#pragma unroll
    for (int r = 0; r < 4; ++r) oidx[r] = out_map[obase + r];
#pragma unroll
    for (int t = 0; t < 4; ++t)
#pragma unroll
      for (int r = 0; r < 4; ++r)
        atomicAdd(out + (size_t)oidx[r] * COUT + t * 16 + lr, acc[t][r]);
  }
}

extern "C" void kernel_launch(void* const* d_in, const int* in_sizes, int n_in,
                              void* d_out, int out_size, void* d_ws, size_t ws_size,
                              hipStream_t stream) {
  const float* x = (const float*)d_in[0];
  const float* W = (const float*)d_in[1];
  const int* in_map = (const int*)d_in[2];
  const int* out_map = (const int*)d_in[3];
  float* out = (float*)d_out;

  // ws layout (256B-aligned slots)
  size_t off = 0;
  auto alloc = [&](size_t bytes) { size_t a = off; off = (off + bytes + 255) & ~(size_t)255; return a; };
  char* ws = (char*)d_ws;
  size_t msg_off    = alloc((size_t)NMSG * 64 * 2);   // 226.5 MB bf16 messages
  size_t list_off   = alloc((size_t)NMSG * 4);        // 7 MB
  size_t count_off  = alloc((size_t)NVOX * 4);        // 1 MB
  size_t offs_off   = alloc((size_t)NVOX * 4);        // 1 MB
  size_t cursor_off = alloc((size_t)NVOX * 4);        // 1 MB
  size_t bsum_off   = alloc((size_t)1024 * 4);

  if (ws_size < off) {
    // Fallback: atomic scatter (round-1 path)
    hipMemsetAsync(d_out, 0, (size_t)out_size * sizeof(float), stream);
    spconv_atomic_kernel<<<dim3(KOFF * TILES_PER_K), dim3(256), 0, stream>>>(
        x, W, in_map, out_map, out);
    return;
  }

  unsigned short* msg = (unsigned short*)(ws + msg_off);
  int* list   = (int*)(ws + list_off);
  int* count  = (int*)(ws + count_off);
  int* offs   = (int*)(ws + offs_off);
  int* cursor = (int*)(ws + cursor_off);
  int* bsum   = (int*)(ws + bsum_off);

  hipMemsetAsync(count, 0, (size_t)NVOX * 4, stream);

  // Phase A (independent of sort chain; same stream serializes anyway)
  gemm_msg_kernel<<<dim3(KOFF * TILES_PER_K), dim3(256), 0, stream>>>(x, W, in_map, msg);

  count_kernel<<<dim3(NMSG / 256), dim3(256), 0, stream>>>(out_map, count);
  scan1_kernel<<<dim3(NVOX / 256), dim3(256), 0, stream>>>(count, offs, bsum);
  scan2_kernel<<<dim3(1), dim3(256), 0, stream>>>(bsum);
  scan3_kernel<<<dim3(NVOX / 256), dim3(256), 0, stream>>>(offs, bsum, cursor);
  scatter_kernel<<<dim3(NMSG / 256), dim3(256), 0, stream>>>(out_map, cursor, list);

  gather_out_kernel<<<dim3(NVOX / 4), dim3(256), 0, stream>>>(msg, list, offs, count, out);
}

// Round 3
// 373.358 us; speedup vs baseline: 1.3787x; 1.3787x over previous
//
#include <hip/hip_runtime.h>
#include <hip/hip_bf16.h>

// Sparse conv, sorted-message pipeline:
//   xcvt:      x f32 -> bf16 (32 MB, L3-resident) to halve gather traffic
//   chain:     invert out_map: count -> scan -> scatter rank  => perm[i] = sorted pos
//   phase A:   gather xb -> bf16 MFMA GEMM per offset -> write msg row i at perm[i]
//   phase B:   per output row: read n CONTIGUOUS 128B msg rows (16B/lane),
//              shfl-reduce across rows, one coalesced write. No indirection.

typedef __attribute__((ext_vector_type(8))) short bf16x8;
typedef __attribute__((ext_vector_type(8))) unsigned short u16x8;
typedef __attribute__((ext_vector_type(4))) float f32x4;

constexpr int KOFF = 27;
constexpr int M = 65536;
constexpr int CIN = 64;
constexpr int COUT = 64;
constexpr int NVOX = 262144;
constexpr int NMSG = KOFF * M;                 // 1,769,472
constexpr int TM_BLOCK = 512;
constexpr int TILES_PER_K = M / TM_BLOCK;      // 128
constexpr int SUBTILES = TM_BLOCK / (4 * 16);  // 8

static __device__ __forceinline__ short f2bf(float f) {
  unsigned u = __builtin_bit_cast(unsigned, f);
  unsigned r = (u + 0x7FFFu + ((u >> 16) & 1u)) >> 16;
  return (short)r;
}
static __device__ __forceinline__ float bf2f(unsigned short h) {
  return __builtin_bit_cast(float, (unsigned)h << 16);
}

// ---------------- x -> bf16 ----------------

__global__ __launch_bounds__(256) void xcvt_kernel(const float* __restrict__ x,
                                                   unsigned short* __restrict__ xb) {
  int i = blockIdx.x * 256 + threadIdx.x;  // 8 floats per thread; grid = NVOX*CIN/8/256
  const float4* p = (const float4*)x + (size_t)i * 2;
  float4 a = p[0], b = p[1];
  u16x8 h;
  h[0] = (unsigned short)f2bf(a.x); h[1] = (unsigned short)f2bf(a.y);
  h[2] = (unsigned short)f2bf(a.z); h[3] = (unsigned short)f2bf(a.w);
  h[4] = (unsigned short)f2bf(b.x); h[5] = (unsigned short)f2bf(b.y);
  h[6] = (unsigned short)f2bf(b.z); h[7] = (unsigned short)f2bf(b.w);
  *(u16x8*)(xb + (size_t)i * 8) = h;
}

// ---------------- sort chain ----------------

__global__ __launch_bounds__(256) void count_kernel(const int* __restrict__ out_map,
                                                    int* __restrict__ count) {
  int i = blockIdx.x * 256 + threadIdx.x;
  atomicAdd(&count[out_map[i]], 1);
}

__global__ __launch_bounds__(256) void scan1_kernel(const int* __restrict__ count,
                                                    int* __restrict__ offsets,
                                                    int* __restrict__ blockSums) {
  __shared__ int s[256];
  int t = threadIdx.x, i = blockIdx.x * 256 + t;
  int c = count[i];
  s[t] = c; __syncthreads();
  for (int off = 1; off < 256; off <<= 1) {
    int add = (t >= off) ? s[t - off] : 0;
    __syncthreads(); s[t] += add; __syncthreads();
  }
  offsets[i] = s[t] - c;
  if (t == 255) blockSums[blockIdx.x] = s[t];
}

__global__ __launch_bounds__(256) void scan2_kernel(int* __restrict__ blockSums) {
  __shared__ int s[256];
  int t = threadIdx.x;
  int v[4]; int sum = 0;
#pragma unroll
  for (int j = 0; j < 4; ++j) { v[j] = blockSums[t * 4 + j]; sum += v[j]; }
  s[t] = sum; __syncthreads();
  for (int off = 1; off < 256; off <<= 1) {
    int add = (t >= off) ? s[t - off] : 0;
    __syncthreads(); s[t] += add; __syncthreads();
  }
  int run = s[t] - sum;
#pragma unroll
  for (int j = 0; j < 4; ++j) { int c = v[j]; blockSums[t * 4 + j] = run; run += c; }
}

__global__ __launch_bounds__(256) void scan3_kernel(int* __restrict__ offsets,
                                                    const int* __restrict__ blockBase,
                                                    int* __restrict__ cursor) {
  int i = blockIdx.x * 256 + threadIdx.x;
  int o = offsets[i] + blockBase[blockIdx.x];
  offsets[i] = o;
  cursor[i] = o;
}

__global__ __launch_bounds__(256) void scatter_kernel(const int* __restrict__ out_map,
                                                      int* __restrict__ cursor,
                                                      int* __restrict__ perm) {
  int i = blockIdx.x * 256 + threadIdx.x;
  perm[i] = atomicAdd(&cursor[out_map[i]], 1);  // sorted position of message i
}

// ---------------- phase A: GEMM -> bf16 messages at sorted positions ----------------

__global__ __launch_bounds__(256) void gemm_msg_kernel(
    const unsigned short* __restrict__ xb, const float* __restrict__ W,
    const int* __restrict__ in_map, const int* __restrict__ perm,
    unsigned short* __restrict__ msg) {
  const int k = blockIdx.x / TILES_PER_K;
  const int mblock = (blockIdx.x % TILES_PER_K) * TM_BLOCK;
  const int wave = threadIdx.x >> 6;
  const int l = threadIdx.x & 63;
  const int g = l >> 4;
  const int lr = l & 15;

  // B fragments: bfrag[t][u][j] = W[k][u*32 + g*8 + j][t*16 + lr]
  bf16x8 bfrag[4][2];
  const float* Wk = W + k * (CIN * COUT);
#pragma unroll
  for (int t = 0; t < 4; ++t)
#pragma unroll
    for (int u = 0; u < 2; ++u)
#pragma unroll
      for (int j = 0; j < 8; ++j)
        bfrag[t][u][j] = f2bf(Wk[(u * 32 + g * 8 + j) * COUT + t * 16 + lr]);

  const int mwave = mblock + wave * (TM_BLOCK / 4);
#pragma unroll 1
  for (int s = 0; s < SUBTILES; ++s) {
    const int mbase = mwave + s * 16;
    const int in_idx = in_map[k * M + mbase + lr];
    const unsigned short* xr = xb + (size_t)in_idx * CIN + g * 8;
    bf16x8 a0 = *(const bf16x8*)(xr);        // channels g*8..g*8+7
    bf16x8 a1 = *(const bf16x8*)(xr + 32);   // channels 32+g*8..+7

    f32x4 acc[4] = {{0.f,0.f,0.f,0.f},{0.f,0.f,0.f,0.f},{0.f,0.f,0.f,0.f},{0.f,0.f,0.f,0.f}};
#pragma unroll
    for (int t = 0; t < 4; ++t) {
      acc[t] = __builtin_amdgcn_mfma_f32_16x16x32_bf16(a0, bfrag[t][0], acc[t], 0, 0, 0);
      acc[t] = __builtin_amdgcn_mfma_f32_16x16x32_bf16(a1, bfrag[t][1], acc[t], 0, 0, 0);
    }

    // Row layout: position p = lr*4 + t holds channel t*16 + lr.
    // Row mbase+g*4+r goes to sorted slot perm[row]; 16 lanes (lr) x 8B = 128B row.
    const int* pr = perm + k * M + mbase + g * 4;
#pragma unroll
    for (int r = 0; r < 4; ++r) {
      ushort4 h;
      h.x = (unsigned short)f2bf(acc[0][r]);
      h.y = (unsigned short)f2bf(acc[1][r]);
      h.z = (unsigned short)f2bf(acc[2][r]);
      h.w = (unsigned short)f2bf(acc[3][r]);
      *(ushort4*)(msg + (size_t)pr[r] * 64 + lr * 4) = h;
    }
  }
}

// ---------------- phase B: contiguous segment sum ----------------

__global__ __launch_bounds__(256) void gather_out_kernel(
    const unsigned short* __restrict__ msg, const int* __restrict__ offs,
    const int* __restrict__ count, float* __restrict__ out) {
  const int o = (blockIdx.x * 256 + threadIdx.x) >> 6;  // one wave per output row
  const int p = threadIdx.x & 63;
  const int n = count[o];
  const int base = offs[o];
  const int rsub = p >> 3;       // row-within-chunk 0..7
  const int qb = (p & 7) * 8;    // position base within row

  float acc[8] = {0.f, 0.f, 0.f, 0.f, 0.f, 0.f, 0.f, 0.f};
  for (int it = 0; it * 8 < n; ++it) {
    int row = it * 8 + rsub;
    int safe = (row < n) ? row : 0;  // clamp OOB lanes to a valid address
    u16x8 v = *(const u16x8*)(msg + (size_t)(base + safe) * 64 + qb);
    if (row < n) {
#pragma unroll
      for (int d = 0; d < 8; ++d) acc[d] += bf2f((unsigned short)v[d]);
    }
  }
  // sum across the 8 row-slots (lanes differing in bits 3..5)
#pragma unroll
  for (int s = 8; s < 64; s <<= 1)
#pragma unroll
    for (int d = 0; d < 8; ++d) acc[d] += __shfl_xor(acc[d], s, 64);

  // lanes 0..7 write; position q=(p&7)*8+d -> channel (d&3)*16 + 2*(p&7) + (d>>2)
  if (p < 8) {
    float* orow = out + (size_t)o * 64 + 2 * p;
    *(float2*)(orow)      = make_float2(acc[0], acc[4]);
    *(float2*)(orow + 16) = make_float2(acc[1], acc[5]);
    *(float2*)(orow + 32) = make_float2(acc[2], acc[6]);
    *(float2*)(orow + 48) = make_float2(acc[3], acc[7]);
  }
}

// ---------------- fallback (round-1 atomic kernel) ----------------

__global__ __launch_bounds__(256) void spconv_atomic_kernel(
    const float* __restrict__ x, const float* __restrict__ W,
    const int* __restrict__ in_map, const int* __restrict__ out_map,
    float* __restrict__ out) {
  const int k = blockIdx.x / TILES_PER_K;
  const int mblock = (blockIdx.x % TILES_PER_K) * TM_BLOCK;
  const int wave = threadIdx.x >> 6;
  const int l = threadIdx.x & 63;
  const int g = l >> 4;
  const int lr = l & 15;
  bf16x8 bfrag[4][2];
  const float* Wk = W + k * (CIN * COUT);
#pragma unroll
  for (int t = 0; t < 4; ++t)
#pragma unroll
    for (int u = 0; u < 2; ++u)
#pragma unroll
      for (int j = 0; j < 8; ++j)
        bfrag[t][u][j] = f2bf(Wk[(u * 32 + g * 8 + j) * COUT + t * 16 + lr]);
  const int mwave = mblock + wave * (TM_BLOCK / 4);
#pragma unroll 1
  for (int s = 0; s < SUBTILES; ++s) {
    const int mbase = mwave + s * 16;
    const int in_idx = in_map[k * M + mbase + lr];
    const float* xr = x + (size_t)in_idx * CIN + g * 8;
    float4 x0 = *(const float4*)(xr);
    float4 x1 = *(const float4*)(xr + 4);
    float4 x2 = *(const float4*)(xr + 32);
    float4 x3 = *(const float4*)(xr + 36);
    bf16x8 a0, a1;
    a0[0]=f2bf(x0.x); a0[1]=f2bf(x0.y); a0[2]=f2bf(x0.z); a0[3]=f2bf(x0.w);
    a0[4]=f2bf(x1.x); a0[5]=f2bf(x1.y); a0[6]=f2bf(x1.z); a0[7]=f2bf(x1.w);
    a1[0]=f2bf(x2.x); a1[1]=f2bf(x2.y); a1[2]=f2bf(x2.z); a1[3]=f2bf(x2.w);
    a1[4]=f2bf(x3.x); a1[5]=f2bf(x3.y); a1[6]=f2bf(x3.z); a1[7]=f2bf(x3.w);
    f32x4 acc[4] = {{0.f,0.f,0.f,0.f},{0.f,0.f,0.f,0.f},{0.f,0.f,0.f,0.f},{0.f,0.f,0.f,0.f}};
#pragma unroll
    for (int t = 0; t < 4; ++t) {
      acc[t] = __builtin_amdgcn_mfma_f32_16x16x32_bf16(a0, bfrag[t][0], acc[t], 0, 0, 0);
      acc[t] = __builtin_amdgcn_mfma_f32_16x16x32_bf16(a1, bfrag[t][1], acc[t], 0, 0, 0);
    }
    const int obase = k * M + mbase + g * 4;
    int oidx[4];
#pragma unroll
    for (int r = 0; r < 4; ++r) oidx[r] = out_map[obase + r];
#pragma unroll
    for (int t = 0; t < 4; ++t)
#pragma unroll
      for (int r = 0; r < 4; ++r)
        atomicAdd(out + (size_t)oidx[r] * COUT + t * 16 + lr, acc[t][r]);
  }
}

extern "C" void kernel_launch(void* const* d_in, const int* in_sizes, int n_in,
                              void* d_out, int out_size, void* d_ws, size_t ws_size,
                              hipStream_t stream) {
  const float* x = (const float*)d_in[0];
  const float* W = (const float*)d_in[1];
  const int* in_map = (const int*)d_in[2];
  const int* out_map = (const int*)d_in[3];
  float* out = (float*)d_out;

  size_t off = 0;
  auto alloc = [&](size_t bytes) { size_t a = off; off = (off + bytes + 255) & ~(size_t)255; return a; };
  char* ws = (char*)d_ws;
  size_t msg_off    = alloc((size_t)NMSG * 64 * 2);      // 226.5 MB
  size_t xb_off     = alloc((size_t)NVOX * CIN * 2);     // 32 MB
  size_t perm_off   = alloc((size_t)NMSG * 4);           // 7 MB
  size_t count_off  = alloc((size_t)NVOX * 4);           // 1 MB
  size_t offs_off   = alloc((size_t)NVOX * 4);           // 1 MB
  size_t cursor_off = alloc((size_t)NVOX * 4);           // 1 MB
  size_t bsum_off   = alloc((size_t)1024 * 4);

  if (ws_size < off) {
    hipMemsetAsync(d_out, 0, (size_t)out_size * sizeof(float), stream);
    spconv_atomic_kernel<<<dim3(KOFF * TILES_PER_K), dim3(256), 0, stream>>>(
        x, W, in_map, out_map, out);
    return;
  }

  unsigned short* msg = (unsigned short*)(ws + msg_off);
  unsigned short* xb  = (unsigned short*)(ws + xb_off);
  int* perm   = (int*)(ws + perm_off);
  int* count  = (int*)(ws + count_off);
  int* offs   = (int*)(ws + offs_off);
  int* cursor = (int*)(ws + cursor_off);
  int* bsum   = (int*)(ws + bsum_off);

  hipMemsetAsync(count, 0, (size_t)NVOX * 4, stream);
  xcvt_kernel<<<dim3(NVOX * CIN / 8 / 256), dim3(256), 0, stream>>>(x, xb);

  count_kernel<<<dim3(NMSG / 256), dim3(256), 0, stream>>>(out_map, count);
  scan1_kernel<<<dim3(NVOX / 256), dim3(256), 0, stream>>>(count, offs, bsum);
  scan2_kernel<<<dim3(1), dim3(256), 0, stream>>>(bsum);
  scan3_kernel<<<dim3(NVOX / 256), dim3(256), 0, stream>>>(offs, bsum, cursor);
  scatter_kernel<<<dim3(NMSG / 256), dim3(256), 0, stream>>>(out_map, cursor, perm);

  gemm_msg_kernel<<<dim3(KOFF * TILES_PER_K), dim3(256), 0, stream>>>(xb, W, in_map, perm, msg);
  gather_out_kernel<<<dim3(NVOX / 4), dim3(256), 0, stream>>>(msg, offs, count, out);
}

// Round 4
// 367.930 us; speedup vs baseline: 1.3990x; 1.0148x over previous
//
#include <hip/hip_runtime.h>

// Sparse conv, workspace-adaptive sorted-message pipeline.
// K offsets split into G groups (G in {1,3,9} chosen so buffers fit ws_size):
//   chain (once): invert out_map per group: count -> scan -> scatter rank
//                 perm[i] = group-local sorted slot of message i
//   per group g:  phase A: gather x -> bf16 MFMA GEMM -> write msg row at perm[i]
//                 phase B: per output row, sum its CONTIGUOUS msg segment,
//                          out = partial (g==0) or out += partial (no atomics)
// Fallback to round-1 atomic kernel only if ws_size < ~61 MB.

typedef __attribute__((ext_vector_type(8))) short bf16x8;
typedef __attribute__((ext_vector_type(8))) unsigned short u16x8;
typedef __attribute__((ext_vector_type(4))) float f32x4;

constexpr int KOFF = 27;
constexpr int M = 65536;
constexpr int CIN = 64;
constexpr int COUT = 64;
constexpr int NVOX = 262144;                   // == 1<<18
constexpr int NMSG = KOFF * M;                 // 1,769,472
constexpr int TM_BLOCK = 512;
constexpr int TILES_PER_K = M / TM_BLOCK;      // 128
constexpr int SUBTILES = TM_BLOCK / (4 * 16);  // 8

static __device__ __forceinline__ short f2bf(float f) {
  unsigned u = __builtin_bit_cast(unsigned, f);
  unsigned r = (u + 0x7FFFu + ((u >> 16) & 1u)) >> 16;
  return (short)r;
}
static __device__ __forceinline__ float bf2f(unsigned short h) {
  return __builtin_bit_cast(float, (unsigned)h << 16);
}

// ---------------- x -> bf16 (optional) ----------------

__global__ __launch_bounds__(256) void xcvt_kernel(const float* __restrict__ x,
                                                   unsigned short* __restrict__ xb) {
  int i = blockIdx.x * 256 + threadIdx.x;  // grid = NVOX*CIN/8/256
  const float4* p = (const float4*)x + (size_t)i * 2;
  float4 a = p[0], b = p[1];
  u16x8 h;
  h[0] = (unsigned short)f2bf(a.x); h[1] = (unsigned short)f2bf(a.y);
  h[2] = (unsigned short)f2bf(a.z); h[3] = (unsigned short)f2bf(a.w);
  h[4] = (unsigned short)f2bf(b.x); h[5] = (unsigned short)f2bf(b.y);
  h[6] = (unsigned short)f2bf(b.z); h[7] = (unsigned short)f2bf(b.w);
  *(u16x8*)(xb + (size_t)i * 8) = h;
}

// ---------------- sort chain (all groups in one pass, grid.y = G) ----------------

__global__ __launch_bounds__(256) void count_kernel(const int* __restrict__ out_map,
                                                    int* __restrict__ count, int mpg) {
  int g = blockIdx.y;
  int li = blockIdx.x * 256 + threadIdx.x;          // local msg idx within group
  atomicAdd(&count[g * NVOX + out_map[g * mpg + li]], 1);
}

__global__ __launch_bounds__(256) void scan1_kernel(const int* __restrict__ count,
                                                    int* __restrict__ offsets,
                                                    int* __restrict__ blockSums) {
  __shared__ int s[256];
  int t = threadIdx.x, i = blockIdx.x * 256 + t;    // grid = G*1024
  int c = count[i];
  s[t] = c; __syncthreads();
  for (int off = 1; off < 256; off <<= 1) {
    int add = (t >= off) ? s[t - off] : 0;
    __syncthreads(); s[t] += add; __syncthreads();
  }
  offsets[i] = s[t] - c;
  if (t == 255) blockSums[blockIdx.x] = s[t];
}

__global__ __launch_bounds__(256) void scan2_kernel(int* __restrict__ bs, int R) {
  // G*1024 block sums, 256 threads, R = G*4 each; two-pass (no runtime-idx array)
  __shared__ int s[256];
  int t = threadIdx.x;
  int sum = 0;
  for (int j = 0; j < R; ++j) sum += bs[t * R + j];
  s[t] = sum; __syncthreads();
  for (int off = 1; off < 256; off <<= 1) {
    int add = (t >= off) ? s[t - off] : 0;
    __syncthreads(); s[t] += add; __syncthreads();
  }
  int run = s[t] - sum;
  for (int j = 0; j < R; ++j) { int c = bs[t * R + j]; bs[t * R + j] = run; run += c; }
}

__global__ __launch_bounds__(256) void scan3_kernel(int* __restrict__ offsets,
                                                    const int* __restrict__ blockBase,
                                                    int* __restrict__ cursor, int mpg) {
  int i = blockIdx.x * 256 + threadIdx.x;           // grid = G*1024
  int g = i >> 18;                                  // NVOX = 1<<18
  int o = offsets[i] + blockBase[blockIdx.x] - g * mpg;  // group-local slot base
  offsets[i] = o;
  cursor[i] = o;
}

__global__ __launch_bounds__(256) void scatter_kernel(const int* __restrict__ out_map,
                                                      int* __restrict__ cursor,
                                                      int* __restrict__ perm, int mpg) {
  int g = blockIdx.y;
  int li = blockIdx.x * 256 + threadIdx.x;
  int i = g * mpg + li;
  perm[i] = atomicAdd(&cursor[g * NVOX + out_map[i]], 1);  // group-local sorted slot
}

// ---------------- phase A: GEMM -> bf16 messages at sorted slots ----------------

template <bool BF16IN>
__global__ __launch_bounds__(256) void gemm_msg_kernel(
    const void* __restrict__ xin, const float* __restrict__ W,
    const int* __restrict__ in_map, const int* __restrict__ perm,
    unsigned short* __restrict__ msg, int g, int KG) {
  const int kl = blockIdx.x / TILES_PER_K;          // grid.x = KG*TILES_PER_K
  const int k = g * KG + kl;
  const int mblock = (blockIdx.x % TILES_PER_K) * TM_BLOCK;
  const int wave = threadIdx.x >> 6;
  const int l = threadIdx.x & 63;
  const int lg = l >> 4;   // 16-lane group 0..3
  const int lr = l & 15;

  // B fragments: bfrag[t][u][j] = W[k][u*32 + lg*8 + j][t*16 + lr]
  bf16x8 bfrag[4][2];
  const float* Wk = W + (size_t)k * (CIN * COUT);
#pragma unroll
  for (int t = 0; t < 4; ++t)
#pragma unroll
    for (int u = 0; u < 2; ++u)
#pragma unroll
      for (int j = 0; j < 8; ++j)
        bfrag[t][u][j] = f2bf(Wk[(u * 32 + lg * 8 + j) * COUT + t * 16 + lr]);

  const int mwave = mblock + wave * (TM_BLOCK / 4);
#pragma unroll 1
  for (int s = 0; s < SUBTILES; ++s) {
    const int mbase = mwave + s * 16;
    const int rowbase = k * M + mbase;
    const int in_idx = in_map[rowbase + lr];

    bf16x8 a0, a1;
    if (BF16IN) {
      const unsigned short* xr = (const unsigned short*)xin + (size_t)in_idx * CIN + lg * 8;
      a0 = *(const bf16x8*)(xr);
      a1 = *(const bf16x8*)(xr + 32);
    } else {
      const float* xr = (const float*)xin + (size_t)in_idx * CIN + lg * 8;
      float4 x0 = *(const float4*)(xr);
      float4 x1 = *(const float4*)(xr + 4);
      float4 x2 = *(const float4*)(xr + 32);
      float4 x3 = *(const float4*)(xr + 36);
      a0[0]=f2bf(x0.x); a0[1]=f2bf(x0.y); a0[2]=f2bf(x0.z); a0[3]=f2bf(x0.w);
      a0[4]=f2bf(x1.x); a0[5]=f2bf(x1.y); a0[6]=f2bf(x1.z); a0[7]=f2bf(x1.w);
      a1[0]=f2bf(x2.x); a1[1]=f2bf(x2.y); a1[2]=f2bf(x2.z); a1[3]=f2bf(x2.w);
      a1[4]=f2bf(x3.x); a1[5]=f2bf(x3.y); a1[6]=f2bf(x3.z); a1[7]=f2bf(x3.w);
    }

    f32x4 acc[4] = {{0.f,0.f,0.f,0.f},{0.f,0.f,0.f,0.f},{0.f,0.f,0.f,0.f},{0.f,0.f,0.f,0.f}};
#pragma unroll
    for (int t = 0; t < 4; ++t) {
      acc[t] = __builtin_amdgcn_mfma_f32_16x16x32_bf16(a0, bfrag[t][0], acc[t], 0, 0, 0);
      acc[t] = __builtin_amdgcn_mfma_f32_16x16x32_bf16(a1, bfrag[t][1], acc[t], 0, 0, 0);
    }

    // Row layout: position p = lr*4 + t holds channel t*16 + lr.
    // D layout: lane holds D[row=lg*4+r][col=lr]; row -> group-local slot perm[row].
    const int* pr = perm + rowbase + lg * 4;
#pragma unroll
    for (int r = 0; r < 4; ++r) {
      ushort4 h;
      h.x = (unsigned short)f2bf(acc[0][r]);
      h.y = (unsigned short)f2bf(acc[1][r]);
      h.z = (unsigned short)f2bf(acc[2][r]);
      h.w = (unsigned short)f2bf(acc[3][r]);
      *(ushort4*)(msg + (size_t)pr[r] * 64 + lr * 4) = h;
    }
  }
}

// ---------------- phase B: contiguous segment sum ----------------

__global__ __launch_bounds__(256) void gather_out_kernel(
    const unsigned short* __restrict__ msg, const int* __restrict__ offs,
    const int* __restrict__ count, float* __restrict__ out, int accumulate) {
  const int o = (blockIdx.x * 256 + threadIdx.x) >> 6;  // one wave per output row
  const int p = threadIdx.x & 63;
  const int n = count[o];
  const int base = offs[o];
  const int rsub = p >> 3;       // row-within-chunk 0..7
  const int qb = (p & 7) * 8;    // position base within row

  float acc[8] = {0.f, 0.f, 0.f, 0.f, 0.f, 0.f, 0.f, 0.f};
  for (int it = 0; it * 8 < n; ++it) {
    int row = it * 8 + rsub;
    int safe = (row < n) ? row : 0;  // OOB lanes re-read a valid line (L1-hit)
    u16x8 v = *(const u16x8*)(msg + (size_t)(base + safe) * 64 + qb);
    if (row < n) {
#pragma unroll
      for (int d = 0; d < 8; ++d) acc[d] += bf2f((unsigned short)v[d]);
    }
  }
  // sum across the 8 row-slots (lane bits 3..5)
#pragma unroll
  for (int s = 8; s < 64; s <<= 1)
#pragma unroll
    for (int d = 0; d < 8; ++d) acc[d] += __shfl_xor(acc[d], s, 64);

  // position q=(p&7)*8+d -> channel (d&3)*16 + 2*(p&7) + (d>>2); lanes 0..7 write
  if (p < 8) {
    float* orow = out + (size_t)o * 64 + 2 * p;
    float2 r0 = make_float2(acc[0], acc[4]);
    float2 r1 = make_float2(acc[1], acc[5]);
    float2 r2 = make_float2(acc[2], acc[6]);
    float2 r3 = make_float2(acc[3], acc[7]);
    if (accumulate) {
      float2 q0 = *(float2*)(orow);      r0.x += q0.x; r0.y += q0.y;
      float2 q1 = *(float2*)(orow + 16); r1.x += q1.x; r1.y += q1.y;
      float2 q2 = *(float2*)(orow + 32); r2.x += q2.x; r2.y += q2.y;
      float2 q3 = *(float2*)(orow + 48); r3.x += q3.x; r3.y += q3.y;
    }
    *(float2*)(orow)      = r0;
    *(float2*)(orow + 16) = r1;
    *(float2*)(orow + 32) = r2;
    *(float2*)(orow + 48) = r3;
  }
}

// ---------------- fallback (round-1 atomic kernel) ----------------

__global__ __launch_bounds__(256) void spconv_atomic_kernel(
    const float* __restrict__ x, const float* __restrict__ W,
    const int* __restrict__ in_map, const int* __restrict__ out_map,
    float* __restrict__ out) {
  const int k = blockIdx.x / TILES_PER_K;
  const int mblock = (blockIdx.x % TILES_PER_K) * TM_BLOCK;
  const int wave = threadIdx.x >> 6;
  const int l = threadIdx.x & 63;
  const int lg = l >> 4;
  const int lr = l & 15;
  bf16x8 bfrag[4][2];
  const float* Wk = W + (size_t)k * (CIN * COUT);
#pragma unroll
  for (int t = 0; t < 4; ++t)
#pragma unroll
    for (int u = 0; u < 2; ++u)
#pragma unroll
      for (int j = 0; j < 8; ++j)
        bfrag[t][u][j] = f2bf(Wk[(u * 32 + lg * 8 + j) * COUT + t * 16 + lr]);
  const int mwave = mblock + wave * (TM_BLOCK / 4);
#pragma unroll 1
  for (int s = 0; s < SUBTILES; ++s) {
    const int mbase = mwave + s * 16;
    const int in_idx = in_map[k * M + mbase + lr];
    const float* xr = x + (size_t)in_idx * CIN + lg * 8;
    float4 x0 = *(const float4*)(xr);
    float4 x1 = *(const float4*)(xr + 4);
    float4 x2 = *(const float4*)(xr + 32);
    float4 x3 = *(const float4*)(xr + 36);
    bf16x8 a0, a1;
    a0[0]=f2bf(x0.x); a0[1]=f2bf(x0.y); a0[2]=f2bf(x0.z); a0[3]=f2bf(x0.w);
    a0[4]=f2bf(x1.x); a0[5]=f2bf(x1.y); a0[6]=f2bf(x1.z); a0[7]=f2bf(x1.w);
    a1[0]=f2bf(x2.x); a1[1]=f2bf(x2.y); a1[2]=f2bf(x2.z); a1[3]=f2bf(x2.w);
    a1[4]=f2bf(x3.x); a1[5]=f2bf(x3.y); a1[6]=f2bf(x3.z); a1[7]=f2bf(x3.w);
    f32x4 acc[4] = {{0.f,0.f,0.f,0.f},{0.f,0.f,0.f,0.f},{0.f,0.f,0.f,0.f},{0.f,0.f,0.f,0.f}};
#pragma unroll
    for (int t = 0; t < 4; ++t) {
      acc[t] = __builtin_amdgcn_mfma_f32_16x16x32_bf16(a0, bfrag[t][0], acc[t], 0, 0, 0);
      acc[t] = __builtin_amdgcn_mfma_f32_16x16x32_bf16(a1, bfrag[t][1], acc[t], 0, 0, 0);
    }
    const int obase = k * M + mbase + lg * 4;
    int oidx[4];
#pragma unroll
    for (int r = 0; r < 4; ++r) oidx[r] = out_map[obase + r];
#pragma unroll
    for (int t = 0; t < 4; ++t)
#pragma unroll
      for (int r = 0; r < 4; ++r)
        atomicAdd(out + (size_t)oidx[r] * COUT + t * 16 + lr, acc[t][r]);
  }
}

extern "C" void kernel_launch(void* const* d_in, const int* in_sizes, int n_in,
                              void* d_out, int out_size, void* d_ws, size_t ws_size,
                              hipStream_t stream) {
  const float* x = (const float*)d_in[0];
  const float* W = (const float*)d_in[1];
  const int* in_map = (const int*)d_in[2];
  const int* out_map = (const int*)d_in[3];
  float* out = (float*)d_out;
  char* ws = (char*)d_ws;

  // Pick the smallest-G plan (fewest passes) that fits; prefer bf16 x-copy.
  const int planG[6] = {1, 1, 3, 3, 9, 9};
  const int planXb[6] = {1, 0, 1, 0, 1, 0};
  int G = -1, useXb = 0;
  size_t msg_off = 0, xb_off = 0, perm_off = 0, count_off = 0, offs_off = 0,
         cursor_off = 0, bsum_off = 0;
  for (int c = 0; c < 6; ++c) {
    size_t off = 0;
    auto al = [&](size_t b) { size_t a = off; off = (off + b + 255) & ~(size_t)255; return a; };
    int g = planG[c];
    int mpg = NMSG / g;
    size_t t_msg = al((size_t)mpg * 128);
    size_t t_xb = planXb[c] ? al((size_t)NVOX * CIN * 2) : 0;
    size_t t_perm = al((size_t)NMSG * 4);
    size_t t_count = al((size_t)g * NVOX * 4);
    size_t t_offs = al((size_t)g * NVOX * 4);
    size_t t_cursor = al((size_t)g * NVOX * 4);
    size_t t_bsum = al((size_t)g * 1024 * 4);
    if (off <= ws_size) {
      G = g; useXb = planXb[c];
      msg_off = t_msg; xb_off = t_xb; perm_off = t_perm; count_off = t_count;
      offs_off = t_offs; cursor_off = t_cursor; bsum_off = t_bsum;
      break;
    }
  }

  if (G < 0) {
    hipMemsetAsync(d_out, 0, (size_t)out_size * sizeof(float), stream);
    spconv_atomic_kernel<<<dim3(KOFF * TILES_PER_K), dim3(256), 0, stream>>>(
        x, W, in_map, out_map, out);
    return;
  }

  const int KG = KOFF / G;
  const int mpg = KG * M;
  unsigned short* msg = (unsigned short*)(ws + msg_off);
  unsigned short* xb = (unsigned short*)(ws + xb_off);
  int* perm = (int*)(ws + perm_off);
  int* count = (int*)(ws + count_off);
  int* offs = (int*)(ws + offs_off);
  int* cursor = (int*)(ws + cursor_off);
  int* bsum = (int*)(ws + bsum_off);

  hipMemsetAsync(count, 0, (size_t)G * NVOX * 4, stream);
  if (useXb)
    xcvt_kernel<<<dim3(NVOX * CIN / 8 / 256), dim3(256), 0, stream>>>(x, xb);

  count_kernel<<<dim3(mpg / 256, G), dim3(256), 0, stream>>>(out_map, count, mpg);
  scan1_kernel<<<dim3(G * 1024), dim3(256), 0, stream>>>(count, offs, bsum);
  scan2_kernel<<<dim3(1), dim3(256), 0, stream>>>(bsum, G * 4);
  scan3_kernel<<<dim3(G * 1024), dim3(256), 0, stream>>>(offs, bsum, cursor, mpg);
  scatter_kernel<<<dim3(mpg / 256, G), dim3(256), 0, stream>>>(out_map, cursor, perm, mpg);

  for (int g = 0; g < G; ++g) {
    if (useXb)
      gemm_msg_kernel<true><<<dim3(KG * TILES_PER_K), dim3(256), 0, stream>>>(
          (const void*)xb, W, in_map, perm, msg, g, KG);
    else
      gemm_msg_kernel<false><<<dim3(KG * TILES_PER_K), dim3(256), 0, stream>>>(
          (const void*)x, W, in_map, perm, msg, g, KG);
    gather_out_kernel<<<dim3(NVOX / 4), dim3(256), 0, stream>>>(
        msg, offs + (size_t)g * NVOX, count + (size_t)g * NVOX, out, g > 0);
  }
}

// Round 5
// 305.283 us; speedup vs baseline: 1.6861x; 1.2052x over previous
//
#include <hip/hip_runtime.h>

// Sparse conv, sorted-message pipeline v3 (fused scatter, 4-row gather).
//   memset count; (opt) xcvt x->bf16
//   count:  histogram of out_map                     (1.77M int atomics)
//   scan1/2/3: exclusive prefix over count -> cursor (segment starts)
//   gemm:   gather x -> bf16 MFMA GEMM per offset; slot = atomicAdd(cursor[out])
//           fused slot assignment (2 atomics/thread up front, shfl-distributed);
//           msg row written at its sorted slot.
//   gather: one wave per 4 output rows; each row's messages are CONTIGUOUS;
//           base = cursorEnd - count. shfl-reduce, direct store (no atomics).

typedef __attribute__((ext_vector_type(8))) short bf16x8;
typedef __attribute__((ext_vector_type(8))) unsigned short u16x8;
typedef __attribute__((ext_vector_type(4))) float f32x4;

constexpr int KOFF = 27;
constexpr int M = 65536;
constexpr int CIN = 64;
constexpr int COUT = 64;
constexpr int NVOX = 262144;
constexpr int NMSG = KOFF * M;                 // 1,769,472
constexpr int TM_BLOCK = 512;
constexpr int TILES_PER_K = M / TM_BLOCK;      // 128
constexpr int SUBTILES = TM_BLOCK / (4 * 16);  // 8

static __device__ __forceinline__ short f2bf(float f) {
  unsigned u = __builtin_bit_cast(unsigned, f);
  unsigned r = (u + 0x7FFFu + ((u >> 16) & 1u)) >> 16;
  return (short)r;
}
static __device__ __forceinline__ float bf2f(unsigned short h) {
  return __builtin_bit_cast(float, (unsigned)h << 16);
}

// ---------------- x -> bf16 (optional) ----------------

__global__ __launch_bounds__(256) void xcvt_kernel(const float* __restrict__ x,
                                                   unsigned short* __restrict__ xb) {
  int i = blockIdx.x * 256 + threadIdx.x;  // grid = NVOX*CIN/8/256
  const float4* p = (const float4*)x + (size_t)i * 2;
  float4 a = p[0], b = p[1];
  u16x8 h;
  h[0] = (unsigned short)f2bf(a.x); h[1] = (unsigned short)f2bf(a.y);
  h[2] = (unsigned short)f2bf(a.z); h[3] = (unsigned short)f2bf(a.w);
  h[4] = (unsigned short)f2bf(b.x); h[5] = (unsigned short)f2bf(b.y);
  h[6] = (unsigned short)f2bf(b.z); h[7] = (unsigned short)f2bf(b.w);
  *(u16x8*)(xb + (size_t)i * 8) = h;
}

// ---------------- histogram + scan ----------------

__global__ __launch_bounds__(256) void count_kernel(const int* __restrict__ out_map,
                                                    int* __restrict__ count) {
  int i = blockIdx.x * 256 + threadIdx.x;  // grid = NMSG/256
  atomicAdd(&count[out_map[i]], 1);
}

__global__ __launch_bounds__(256) void scan1_kernel(const int* __restrict__ count,
                                                    int* __restrict__ cursor,
                                                    int* __restrict__ blockSums) {
  __shared__ int s[256];
  int t = threadIdx.x, i = blockIdx.x * 256 + t;  // grid = NVOX/256 = 1024
  int c = count[i];
  s[t] = c; __syncthreads();
  for (int off = 1; off < 256; off <<= 1) {
    int add = (t >= off) ? s[t - off] : 0;
    __syncthreads(); s[t] += add; __syncthreads();
  }
  cursor[i] = s[t] - c;  // block-local exclusive
  if (t == 255) blockSums[blockIdx.x] = s[t];
}

__global__ __launch_bounds__(256) void scan2_kernel(int* __restrict__ bs) {
  // 1024 block sums -> exclusive bases, in place
  __shared__ int s[256];
  int t = threadIdx.x;
  int v0 = bs[t*4], v1 = bs[t*4+1], v2 = bs[t*4+2], v3 = bs[t*4+3];
  int sum = v0 + v1 + v2 + v3;
  s[t] = sum; __syncthreads();
  for (int off = 1; off < 256; off <<= 1) {
    int add = (t >= off) ? s[t - off] : 0;
    __syncthreads(); s[t] += add; __syncthreads();
  }
  int run = s[t] - sum;
  bs[t*4] = run; run += v0;
  bs[t*4+1] = run; run += v1;
  bs[t*4+2] = run; run += v2;
  bs[t*4+3] = run;
}

__global__ __launch_bounds__(256) void scan3_kernel(int* __restrict__ cursor,
                                                    const int* __restrict__ blockBase) {
  int i = blockIdx.x * 256 + threadIdx.x;  // grid = 1024
  cursor[i] += blockBase[blockIdx.x];      // global segment start
}

// ---------------- phase A: GEMM -> bf16 messages at sorted slots (fused scatter) --------

template <bool BF16IN>
__global__ __launch_bounds__(256) void gemm_msg_kernel(
    const void* __restrict__ xin, const float* __restrict__ W,
    const int* __restrict__ in_map, const int* __restrict__ out_map,
    int* __restrict__ cursor, unsigned short* __restrict__ msg) {
  const int k = blockIdx.x / TILES_PER_K;
  const int mblock = (blockIdx.x % TILES_PER_K) * TM_BLOCK;
  const int wave = threadIdx.x >> 6;
  const int l = threadIdx.x & 63;
  const int lg = l >> 4;   // 16-lane group 0..3
  const int lr = l & 15;

  // B fragments: bfrag[t][u][j] = W[k][u*32 + lg*8 + j][t*16 + lr]
  bf16x8 bfrag[4][2];
  const float* Wk = W + (size_t)k * (CIN * COUT);
#pragma unroll
  for (int t = 0; t < 4; ++t)
#pragma unroll
    for (int u = 0; u < 2; ++u)
#pragma unroll
      for (int j = 0; j < 8; ++j)
        bfrag[t][u][j] = f2bf(Wk[(u * 32 + lg * 8 + j) * COUT + t * 16 + lr]);

  const int mwave = mblock + wave * (TM_BLOCK / 4);  // this wave's 128 rows
  // Fused scatter: grab sorted slots for all 128 rows up front (2 atomics/lane),
  // distribute to consumers via shfl inside the subtile loop.
  const int rb = k * M + mwave;
  int slotA = atomicAdd(&cursor[out_map[rb + l]], 1);        // rows 0..63
  int slotB = atomicAdd(&cursor[out_map[rb + 64 + l]], 1);   // rows 64..127

#pragma unroll 1
  for (int s = 0; s < SUBTILES; ++s) {
    const int mbase = mwave + s * 16;
    const int in_idx = in_map[k * M + mbase + lr];

    bf16x8 a0, a1;
    if (BF16IN) {
      const unsigned short* xr = (const unsigned short*)xin + (size_t)in_idx * CIN + lg * 8;
      a0 = *(const bf16x8*)(xr);
      a1 = *(const bf16x8*)(xr + 32);
    } else {
      const float* xr = (const float*)xin + (size_t)in_idx * CIN + lg * 8;
      float4 x0 = *(const float4*)(xr);
      float4 x1 = *(const float4*)(xr + 4);
      float4 x2 = *(const float4*)(xr + 32);
      float4 x3 = *(const float4*)(xr + 36);
      a0[0]=f2bf(x0.x); a0[1]=f2bf(x0.y); a0[2]=f2bf(x0.z); a0[3]=f2bf(x0.w);
      a0[4]=f2bf(x1.x); a0[5]=f2bf(x1.y); a0[6]=f2bf(x1.z); a0[7]=f2bf(x1.w);
      a1[0]=f2bf(x2.x); a1[1]=f2bf(x2.y); a1[2]=f2bf(x2.z); a1[3]=f2bf(x2.w);
      a1[4]=f2bf(x3.x); a1[5]=f2bf(x3.y); a1[6]=f2bf(x3.z); a1[7]=f2bf(x3.w);
    }

    f32x4 acc[4] = {{0.f,0.f,0.f,0.f},{0.f,0.f,0.f,0.f},{0.f,0.f,0.f,0.f},{0.f,0.f,0.f,0.f}};
#pragma unroll
    for (int t = 0; t < 4; ++t) {
      acc[t] = __builtin_amdgcn_mfma_f32_16x16x32_bf16(a0, bfrag[t][0], acc[t], 0, 0, 0);
      acc[t] = __builtin_amdgcn_mfma_f32_16x16x32_bf16(a1, bfrag[t][1], acc[t], 0, 0, 0);
    }

    // Row layout: position p = lr*4 + t holds channel t*16 + lr.
    // D layout: lane holds D[row=lg*4+r][col=lr]; slot from shfl of slotA/slotB.
#pragma unroll
    for (int r = 0; r < 4; ++r) {
      const int idx = s * 16 + lg * 4 + r;  // wave-row 0..127
      const int sl = (s < 4) ? __shfl(slotA, idx & 63, 64)
                             : __shfl(slotB, idx & 63, 64);
      ushort4 h;
      h.x = (unsigned short)f2bf(acc[0][r]);
      h.y = (unsigned short)f2bf(acc[1][r]);
      h.z = (unsigned short)f2bf(acc[2][r]);
      h.w = (unsigned short)f2bf(acc[3][r]);
      *(ushort4*)(msg + (size_t)sl * 64 + lr * 4) = h;
    }
  }
}

// ---------------- phase B: contiguous segment sum, 4 rows per wave ----------------

__global__ __launch_bounds__(256) void gather_out_kernel(
    const unsigned short* __restrict__ msg, const int* __restrict__ cursorEnd,
    const int* __restrict__ count, float* __restrict__ out) {
  const int wid = (blockIdx.x * 256 + threadIdx.x) >> 6;  // grid = NVOX/16 blocks
  const int p = threadIdx.x & 63;
  const int o0 = wid * 4;
  const int rsub = p >> 3;       // row-within-chunk 0..7
  const int qb = (p & 7) * 8;    // position base within row

  int n[4], base[4];
#pragma unroll
  for (int j = 0; j < 4; ++j) {
    n[j] = count[o0 + j];
    base[j] = cursorEnd[o0 + j] - n[j];  // segment start
  }

  float acc[4][8] = {};
  // First chunk for all 4 rows: independent loads -> depth-4 MLP.
#pragma unroll
  for (int j = 0; j < 4; ++j) {
    int safe = (rsub < n[j]) ? rsub : 0;
    u16x8 v = *(const u16x8*)(msg + (size_t)(base[j] + safe) * 64 + qb);
    if (rsub < n[j]) {
#pragma unroll
      for (int d = 0; d < 8; ++d) acc[j][d] += bf2f((unsigned short)v[d]);
    }
  }
  // Rare tail (n > 8); wave-uniform branch.
#pragma unroll
  for (int j = 0; j < 4; ++j) {
    for (int it = 1; it * 8 < n[j]; ++it) {
      int row = it * 8 + rsub;
      int safe = (row < n[j]) ? row : 0;
      u16x8 v = *(const u16x8*)(msg + (size_t)(base[j] + safe) * 64 + qb);
      if (row < n[j]) {
#pragma unroll
        for (int d = 0; d < 8; ++d) acc[j][d] += bf2f((unsigned short)v[d]);
      }
    }
  }

  // Sum across the 8 row-slots (lane bits 3..5).
#pragma unroll
  for (int j = 0; j < 4; ++j)
#pragma unroll
    for (int s = 8; s < 64; s <<= 1)
#pragma unroll
      for (int d = 0; d < 8; ++d) acc[j][d] += __shfl_xor(acc[j][d], s, 64);

  // position q=(p&7)*8+d -> channel (d&3)*16 + 2*(p&7) + (d>>2); lanes 0..7 write.
  if (p < 8) {
#pragma unroll
    for (int j = 0; j < 4; ++j) {
      float* orow = out + (size_t)(o0 + j) * 64 + 2 * p;
      *(float2*)(orow)      = make_float2(acc[j][0], acc[j][4]);
      *(float2*)(orow + 16) = make_float2(acc[j][1], acc[j][5]);
      *(float2*)(orow + 32) = make_float2(acc[j][2], acc[j][6]);
      *(float2*)(orow + 48) = make_float2(acc[j][3], acc[j][7]);
    }
  }
}

// ---------------- fallback (atomic scatter) ----------------

__global__ __launch_bounds__(256) void spconv_atomic_kernel(
    const float* __restrict__ x, const float* __restrict__ W,
    const int* __restrict__ in_map, const int* __restrict__ out_map,
    float* __restrict__ out) {
  const int k = blockIdx.x / TILES_PER_K;
  const int mblock = (blockIdx.x % TILES_PER_K) * TM_BLOCK;
  const int wave = threadIdx.x >> 6;
  const int l = threadIdx.x & 63;
  const int lg = l >> 4;
  const int lr = l & 15;
  bf16x8 bfrag[4][2];
  const float* Wk = W + (size_t)k * (CIN * COUT);
#pragma unroll
  for (int t = 0; t < 4; ++t)
#pragma unroll
    for (int u = 0; u < 2; ++u)
#pragma unroll
      for (int j = 0; j < 8; ++j)
        bfrag[t][u][j] = f2bf(Wk[(u * 32 + lg * 8 + j) * COUT + t * 16 + lr]);
  const int mwave = mblock + wave * (TM_BLOCK / 4);
#pragma unroll 1
  for (int s = 0; s < SUBTILES; ++s) {
    const int mbase = mwave + s * 16;
    const int in_idx = in_map[k * M + mbase + lr];
    const float* xr = x + (size_t)in_idx * CIN + lg * 8;
    float4 x0 = *(const float4*)(xr);
    float4 x1 = *(const float4*)(xr + 4);
    float4 x2 = *(const float4*)(xr + 32);
    float4 x3 = *(const float4*)(xr + 36);
    bf16x8 a0, a1;
    a0[0]=f2bf(x0.x); a0[1]=f2bf(x0.y); a0[2]=f2bf(x0.z); a0[3]=f2bf(x0.w);
    a0[4]=f2bf(x1.x); a0[5]=f2bf(x1.y); a0[6]=f2bf(x1.z); a0[7]=f2bf(x1.w);
    a1[0]=f2bf(x2.x); a1[1]=f2bf(x2.y); a1[2]=f2bf(x2.z); a1[3]=f2bf(x2.w);
    a1[4]=f2bf(x3.x); a1[5]=f2bf(x3.y); a1[6]=f2bf(x3.z); a1[7]=f2bf(x3.w);
    f32x4 acc[4] = {{0.f,0.f,0.f,0.f},{0.f,0.f,0.f,0.f},{0.f,0.f,0.f,0.f},{0.f,0.f,0.f,0.f}};
#pragma unroll
    for (int t = 0; t < 4; ++t) {
      acc[t] = __builtin_amdgcn_mfma_f32_16x16x32_bf16(a0, bfrag[t][0], acc[t], 0, 0, 0);
      acc[t] = __builtin_amdgcn_mfma_f32_16x16x32_bf16(a1, bfrag[t][1], acc[t], 0, 0, 0);
    }
    const int obase = k * M + mbase + lg * 4;
    int oidx[4];
#pragma unroll
    for (int r = 0; r < 4; ++r) oidx[r] = out_map[obase + r];
#pragma unroll
    for (int t = 0; t < 4; ++t)
#pragma unroll
      for (int r = 0; r < 4; ++r)
        atomicAdd(out + (size_t)oidx[r] * COUT + t * 16 + lr, acc[t][r]);
  }
}

extern "C" void kernel_launch(void* const* d_in, const int* in_sizes, int n_in,
                              void* d_out, int out_size, void* d_ws, size_t ws_size,
                              hipStream_t stream) {
  const float* x = (const float*)d_in[0];
  const float* W = (const float*)d_in[1];
  const int* in_map = (const int*)d_in[2];
  const int* out_map = (const int*)d_in[3];
  float* out = (float*)d_out;
  char* ws = (char*)d_ws;

  const size_t msg_b = (size_t)NMSG * 128;        // 226.5 MB
  const size_t xb_b = (size_t)NVOX * CIN * 2;     // 33.6 MB
  const size_t cnt_b = (size_t)NVOX * 4;          // 1 MB
  auto pad = [](size_t b) { return (b + 255) & ~(size_t)255; };

  // P0: with bf16 x-copy; P1: without. Both drop perm/offs vs round 4.
  size_t need_p1 = pad(msg_b) + 2 * pad(cnt_b) + pad(1024 * 4);
  size_t need_p0 = need_p1 + pad(xb_b);
  bool useXb = (ws_size >= need_p0);

  if (ws_size < need_p1) {
    hipMemsetAsync(d_out, 0, (size_t)out_size * sizeof(float), stream);
    spconv_atomic_kernel<<<dim3(KOFF * TILES_PER_K), dim3(256), 0, stream>>>(
        x, W, in_map, out_map, out);
    return;
  }

  size_t off = 0;
  unsigned short* msg = (unsigned short*)(ws + off); off += pad(msg_b);
  unsigned short* xb = nullptr;
  if (useXb) { xb = (unsigned short*)(ws + off); off += pad(xb_b); }
  int* count  = (int*)(ws + off); off += pad(cnt_b);
  int* cursor = (int*)(ws + off); off += pad(cnt_b);
  int* bsum   = (int*)(ws + off);

  hipMemsetAsync(count, 0, cnt_b, stream);
  if (useXb)
    xcvt_kernel<<<dim3(NVOX * CIN / 8 / 256), dim3(256), 0, stream>>>(x, xb);

  count_kernel<<<dim3(NMSG / 256), dim3(256), 0, stream>>>(out_map, count);
  scan1_kernel<<<dim3(NVOX / 256), dim3(256), 0, stream>>>(count, cursor, bsum);
  scan2_kernel<<<dim3(1), dim3(256), 0, stream>>>(bsum);
  scan3_kernel<<<dim3(NVOX / 256), dim3(256), 0, stream>>>(cursor, bsum);

  if (useXb)
    gemm_msg_kernel<true><<<dim3(KOFF * TILES_PER_K), dim3(256), 0, stream>>>(
        (const void*)xb, W, in_map, out_map, cursor, msg);
  else
    gemm_msg_kernel<false><<<dim3(KOFF * TILES_PER_K), dim3(256), 0, stream>>>(
        (const void*)x, W, in_map, out_map, cursor, msg);

  gather_out_kernel<<<dim3(NVOX / 16), dim3(256), 0, stream>>>(msg, cursor, count, out);
}